// Round 6
// baseline (318.046 us; speedup 1.0000x reference)
//
#include <hip/hip_runtime.h>

using u16 = unsigned short;
using u32 = unsigned int;

// Problem constants: B=8, T=2048, C=1024
constexpr int Cdim  = 1024;
constexpr int Bn    = 8;
constexpr int Tn    = 2048;
constexpr int Mrows = Bn * Tn;          // 16384 rows in all GEMMs
constexpr int NCH   = 64;               // wkv chunks per chain
constexpr int CLEN  = Tn / NCH;         // 32 steps per chunk
constexpr int CP    = Cdim / 2;         // 512 channel-pairs

// ---------- bf16 helpers (bit-level, RNE) ----------
__device__ inline u16 f2bf(float x) {
    u32 u = __float_as_uint(x);
    u += 0x7fffu + ((u >> 16) & 1u);
    return (u16)(u >> 16);
}
__device__ inline float bf2f(u16 x) {
    return __uint_as_float(((u32)x) << 16);
}

// ---------- fp32 -> bf16 cast: X + 3 weights, ONE dispatch ----------
__global__ __launch_bounds__(256)
void cast_all(const float* __restrict__ x, const float* __restrict__ vw,
              const float* __restrict__ rw, const float* __restrict__ ow,
              u16* __restrict__ Xb, u16* __restrict__ Wvr, u16* __restrict__ Wo)
{
    const int b = blockIdx.x;
    const float4* src;
    ushort4*      dst;
    int i;
    if (b < 16384)      { src = (const float4*)x;  dst = (ushort4*)Xb;                i = b * 256 + threadIdx.x; }
    else if (b < 17408) { src = (const float4*)vw; dst = (ushort4*)Wvr;               i = (b - 16384) * 256 + threadIdx.x; }
    else if (b < 18432) { src = (const float4*)rw; dst = (ushort4*)(Wvr + 1048576);   i = (b - 17408) * 256 + threadIdx.x; }
    else                { src = (const float4*)ow; dst = (ushort4*)Wo;                i = (b - 18432) * 256 + threadIdx.x; }
    float4 v = src[i];
    ushort4 o;
    o.x = f2bf(v.x); o.y = f2bf(v.y); o.z = f2bf(v.z); o.w = f2bf(v.w);
    dst[i] = o;
}

// ---------- MFMA bf16 NT-GEMM, 256x256 tile, B-direct-from-L2 ----------
// A staged in LDS (3 x 32KB buffers, 2 tiles ahead). B fragments loaded
// straight global->VGPR (weights are L2-resident), register-double-buffered
// one K-tile ahead. 2 phases per K-tile, ONE barrier per phase.
typedef __bf16 bf16x8 __attribute__((ext_vector_type(8)));
typedef float  f32x4  __attribute__((ext_vector_type(4)));

#define SB0() __builtin_amdgcn_sched_barrier(0)
#define BARRIER() do { SB0(); __builtin_amdgcn_s_barrier(); SB0(); } while (0)
#define LGKM0()   do { asm volatile("s_waitcnt lgkmcnt(0)" ::: "memory"); SB0(); } while (0)
#define VMW(n)    do { asm volatile("s_waitcnt vmcnt(" #n ")" ::: "memory"); SB0(); } while (0)

__device__ __forceinline__ void gload16(const u16* g, char* l) {
    __builtin_amdgcn_global_load_lds(
        (const __attribute__((address_space(1))) void*)g,
        (__attribute__((address_space(3))) void*)l, 16, 0, 0);
}

// One C-quadrant x K=64: 16 MFMAs, setprio-wrapped (T5).
template<int IB, int JB>
__device__ __forceinline__ void mma_quad(f32x4 (&acc)[8][4],
                                         const bf16x8 (&aF)[4][2],
                                         const bf16x8 (&bF)[4][2]) {
    __builtin_amdgcn_s_setprio(1);
    #pragma unroll
    for (int i = 0; i < 4; ++i)
        #pragma unroll
        for (int j = 0; j < 2; ++j) {
            acc[IB + i][JB + j] = __builtin_amdgcn_mfma_f32_16x16x32_bf16(
                aF[i][0], bF[JB + j][0], acc[IB + i][JB + j], 0, 0, 0);
            acc[IB + i][JB + j] = __builtin_amdgcn_mfma_f32_16x16x32_bf16(
                aF[i][1], bF[JB + j][1], acc[IB + i][JB + j], 0, 0, 0);
        }
    __builtin_amdgcn_s_setprio(0);
}

// Stage one 256x64 A K-tile (4 x global_load_lds per thread).
__device__ __forceinline__ void stageA(const u16* aG, int k0, char* dst) {
    gload16(aG + k0,              dst);            // rows   0- 63
    gload16(aG + 128 * Cdim + k0, dst + 16384);    // rows 128-191
    gload16(aG +  64 * Cdim + k0, dst + 8192);     // rows  64-127
    gload16(aG + 192 * Cdim + k0, dst + 24576);    // rows 192-255
}

// Per-wave issue stream per steady tile t:
//   ph1: B01(t+1) x4 [reg]      ph2: B23(t+1) x4 [reg], A(t+2) x4 [lds]
// Induction invariant entering ph1(t): outstanding = [B01(t)4 B23(t)4 A(t+1)4].
//   ph1: +4 -> 16; VMW(8) retires B01(t),B23(t)  (operands of this tile)
//   ph2: +8 -> 16; VMW(12) retires A(t+1) before the barrier (next tile's LDS)
// All waits have >=1 phase (~800cyc) cover vs L2 (~400) and >=1 tile vs HBM.
// B-register consumers are additionally auto-waited by the compiler, so the
// counted VMWs only need to be correct for the A-staging stream.
// MODE: 0 = steady, 1 = tile 14 (B issue, no A stage, ph2 VMW(8)), 2 = tail.
template<int MODE>
__device__ __forceinline__ void tile_step(f32x4 (&acc)[8][4],
                                          bf16x8 (&bfC)[4][2], bf16x8 (&bfN)[4][2],
                                          const u16* __restrict__ aG,
                                          const u16* __restrict__ bGf,
                                          char* stBase, const char* aRd,
                                          int x0, int cb, int st, int ktn)
{
    bf16x8 aF[4][2];
    // ---- phase 1: aF-low reads; issue B01(t+1); quads (0,0)+(0,2) ----
    #pragma unroll
    for (int i = 0; i < 4; ++i) {
        aF[i][0] = *(const bf16x8*)(aRd + cb + i * 2048 + x0);
        aF[i][1] = *(const bf16x8*)(aRd + cb + i * 2048 + (x0 ^ 64));
    }
    if constexpr (MODE < 2) {
        bfN[0][0] = *(const bf16x8*)(bGf + 0 * 16 * Cdim + ktn);
        bfN[0][1] = *(const bf16x8*)(bGf + 0 * 16 * Cdim + ktn + 32);
        bfN[1][0] = *(const bf16x8*)(bGf + 1 * 16 * Cdim + ktn);
        bfN[1][1] = *(const bf16x8*)(bGf + 1 * 16 * Cdim + ktn + 32);
        SB0();
        VMW(8);
    }
    LGKM0();
    mma_quad<0, 0>(acc, aF, bfC);
    mma_quad<0, 2>(acc, aF, bfC);
    BARRIER();

    // ---- phase 2: aF-high reads; issue B23(t+1) + stage A(t+2); quads (4,0)+(4,2) ----
    #pragma unroll
    for (int i = 0; i < 4; ++i) {
        aF[i][0] = *(const bf16x8*)(aRd + cb + (4 + i) * 2048 + x0);
        aF[i][1] = *(const bf16x8*)(aRd + cb + (4 + i) * 2048 + (x0 ^ 64));
    }
    if constexpr (MODE < 2) {
        bfN[2][0] = *(const bf16x8*)(bGf + 2 * 16 * Cdim + ktn);
        bfN[2][1] = *(const bf16x8*)(bGf + 2 * 16 * Cdim + ktn + 32);
        bfN[3][0] = *(const bf16x8*)(bGf + 3 * 16 * Cdim + ktn);
        bfN[3][1] = *(const bf16x8*)(bGf + 3 * 16 * Cdim + ktn + 32);
    }
    SB0();
    if constexpr (MODE == 0) {
        stageA(aG, ktn + 64, stBase + st);
        SB0();
    }
    LGKM0();
    mma_quad<4, 0>(acc, aF, bfC);
    mma_quad<4, 2>(acc, aF, bfC);
    if constexpr (MODE == 0)      { VMW(12); }
    else if constexpr (MODE == 1) { VMW(8); }
    if constexpr (MODE < 2) BARRIER();
}

// Core: 16 K-tiles. aRd = smem + wr*16384 + l15*128; stBase = smem + wave*1024.
__device__ __forceinline__ void gemm_core2(const u16* __restrict__ aG,
                                           const u16* __restrict__ bGf,
                                           char* stBase, const char* aRd,
                                           int x0, f32x4 (&acc)[8][4])
{
    bf16x8 bfA[4][2], bfB[4][2];

    // ---- prologue: B(0) -> regs; stage A(0) (buf0), A(1) (buf1) ----
    #pragma unroll
    for (int j = 0; j < 4; ++j) {
        bfA[j][0] = *(const bf16x8*)(bGf + j * 16 * Cdim);
        bfA[j][1] = *(const bf16x8*)(bGf + j * 16 * Cdim + 32);
    }
    SB0();
    stageA(aG, 0, stBase);
    SB0();
    stageA(aG, 64, stBase + 32768);
    SB0();
    VMW(4);        // retire B(0) regs + A(0); A(1) stays in flight
    BARRIER();

    int cb = 0, st = 65536, ktn = 64;
    #pragma unroll 1
    for (int it = 0; it < 7; ++it) {
        tile_step<0>(acc, bfA, bfB, aG, bGf, stBase, aRd, x0, cb, st, ktn);
        cb += 32768; if (cb == 98304) cb = 0;
        st += 32768; if (st == 98304) st = 0;
        ktn += 64;
        tile_step<0>(acc, bfB, bfA, aG, bGf, stBase, aRd, x0, cb, st, ktn);
        cb += 32768; if (cb == 98304) cb = 0;
        st += 32768; if (st == 98304) st = 0;
        ktn += 64;
    }
    // tile 14: load B(15), no A stage
    tile_step<1>(acc, bfA, bfB, aG, bGf, stBase, aRd, x0, cb, st, ktn);
    cb += 32768; if (cb == 98304) cb = 0;
    ktn += 64;
    // tile 15: tail
    tile_step<2>(acc, bfB, bfA, aG, bGf, stBase, aRd, x0, cb, st, ktn);
}

// ---------- GEMM1: [V|R] = X @ [Wv;Wr]^T, N=2048, sigmoid on R half ----------
__global__ __launch_bounds__(512, 2)
void gemm_vr(const u16* __restrict__ A, const u16* __restrict__ Wvr,
             u16* __restrict__ Vb, u16* __restrict__ Rb)
{
    __shared__ alignas(16) char smem[98304];
    const int wave = threadIdx.x >> 6;
    const int lane = threadIdx.x & 63;

    // bijective XCD swizzle: 512 blocks, 8 XCDs, 64 m-tiles x 8 n-tiles
    const int b    = blockIdx.x;
    const int xcd  = b & 7;
    const int sIdx = b >> 3;                 // 0..63
    const int mt   = xcd * 8 + (sIdx >> 3);  // 0..63
    const int nt   = sIdx & 7;               // 0..7
    const int m0   = mt * 256;
    const int n0   = nt * 256;

    const int l15 = lane & 15;
    const int g   = lane >> 4;
    const int wr  = wave >> 2;
    const int wc  = wave & 3;
    const int tid = wave * 64 + lane;

    const int srow = tid >> 3;
    const int kcol = ((tid & 7) ^ (srow & 7)) * 8;
    const u16* aG  = A + (size_t)(m0 + srow) * Cdim + kcol;
    const u16* bGf = Wvr + (size_t)(n0 + wc * 64 + l15) * Cdim + g * 8;
    char* stBase = smem + wave * 1024;

    const int x0 = (g ^ (l15 & 7)) * 16;
    const char* aRd = smem + wr * 16384 + l15 * 128;

    f32x4 acc[8][4] = {};
    gemm_core2(aG, bGf, stBase, aRd, x0, acc);

    const bool isR = (nt >= 4);
    u16* dst = isR ? Rb : Vb;
    const int cbase = n0 - (isR ? 1024 : 0) + wc * 64 + l15;
    const int rbase = m0 + wr * 128 + g * 4;
    #pragma unroll
    for (int i = 0; i < 8; ++i)
        #pragma unroll
        for (int j = 0; j < 4; ++j)
            #pragma unroll
            for (int r = 0; r < 4; ++r) {
                float v = acc[i][j][r];
                if (isR) v = 1.f / (1.f + __expf(-v));
                dst[(size_t)(rbase + i * 16 + r) * Cdim + cbase + j * 16] = f2bf(v);
            }
}

// ---------- GEMM2: out = Y @ Wo^T, N=1024, fp32 out ----------
__global__ __launch_bounds__(512, 2)
void gemm_out(const u16* __restrict__ A, const u16* __restrict__ Wo,
              float* __restrict__ O)
{
    __shared__ alignas(16) char smem[98304];
    const int wave = threadIdx.x >> 6;
    const int lane = threadIdx.x & 63;

    const int b    = blockIdx.x;
    const int xcd  = b & 7;
    const int s    = b >> 3;                 // 0..31
    const int mt   = xcd * 8 + (s >> 2);     // 0..63
    const int nt   = s & 3;                  // 0..3
    const int m0   = mt * 256;

    const int l15 = lane & 15;
    const int g   = lane >> 4;
    const int wr  = wave >> 2;
    const int wc  = wave & 3;
    const int tid = wave * 64 + lane;

    const int srow = tid >> 3;
    const int kcol = ((tid & 7) ^ (srow & 7)) * 8;
    const u16* aG  = A  + (size_t)(m0 + srow) * Cdim + kcol;
    const u16* bGf = Wo + (size_t)(nt * 256 + wc * 64 + l15) * Cdim + g * 8;
    char* stBase = smem + wave * 1024;

    const int x0 = (g ^ (l15 & 7)) * 16;
    const char* aRd = smem + wr * 16384 + l15 * 128;

    f32x4 acc[8][4] = {};
    gemm_core2(aG, bGf, stBase, aRd, x0, acc);

    const int cbase = nt * 256 + wc * 64 + l15;
    const int rbase = m0 + wr * 128 + g * 4;
    #pragma unroll
    for (int i = 0; i < 8; ++i)
        #pragma unroll
        for (int j = 0; j < 4; ++j)
            #pragma unroll
            for (int r = 0; r < 4; ++r)
                O[(size_t)(rbase + i * 16 + r) * Cdim + cbase + j * 16] = acc[i][j][r];
}

// ---------- WKV: constant-coefficient linear recurrence, chunk-parallel ----------
__global__ __launch_bounds__(256)
void wkv_pass1(const u16* __restrict__ Vb, const float* __restrict__ td,
               float2* __restrict__ Sa)
{
    const int t = blockIdx.x * 256 + threadIdx.x;     // 0..262143
    const int cp    = t & (CP - 1);                   // 0..511
    const int chunk = (t >> 9) & (NCH - 1);           // 0..63
    const int b     = t >> 15;                        // 0..7

    const float2 tdc = *(const float2*)&td[cp * 2];
    const float lam0 = __expf(-fmaxf(tdc.x, 0.f)), mu0 = __expf(fminf(tdc.x, 0.f));
    const float lam1 = __expf(-fmaxf(tdc.y, 0.f)), mu1 = __expf(fminf(tdc.y, 0.f));

    const u32* V32 = (const u32*)Vb;
    size_t idx = ((size_t)(b * Tn + chunk * CLEN)) * CP + cp;
    float s0 = 0.f, s1 = 0.f;
    #pragma unroll 4
    for (int i = 0; i < CLEN; ++i, idx += CP) {
        const u32 vv = V32[idx];
        s0 = lam0 * s0 + mu0 * bf2f((u16)vv);
        s1 = lam1 * s1 + mu1 * bf2f((u16)(vv >> 16));
    }
    Sa[t] = make_float2(s0, s1);    // layout [b][chunk][cp] == t
}

__global__ __launch_bounds__(256)
void wkv_pass2(const u16* __restrict__ Vb, const u16* __restrict__ Rb,
               const float* __restrict__ td, const float* __restrict__ tf,
               const float2* __restrict__ Sa, u16* __restrict__ Y)
{
    const int t = blockIdx.x * 256 + threadIdx.x;
    const int cp    = t & (CP - 1);
    const int chunk = (t >> 9) & (NCH - 1);
    const int b     = t >> 15;

    const float2 tdc = *(const float2*)&td[cp * 2];
    const float2 tfc = *(const float2*)&tf[cp * 2];

    const float lam0 = __expf(-fmaxf(tdc.x, 0.f)), mu0 = __expf(fminf(tdc.x, 0.f));
    const float lam1 = __expf(-fmaxf(tdc.y, 0.f)), mu1 = __expf(fminf(tdc.y, 0.f));
    const float e10  = __expf(-fmaxf(tfc.x, 0.f)), e20 = __expf(fminf(tfc.x, 0.f));
    const float e11  = __expf(-fmaxf(tfc.y, 0.f)), e21 = __expf(fminf(tfc.y, 0.f));
    const float lamL0 = __expf(-(float)CLEN * fmaxf(tdc.x, 0.f));
    const float lamL1 = __expf(-(float)CLEN * fmaxf(tdc.y, 0.f));
    const float Sb0 = (fabsf(1.f - lam0) < 1e-9f) ? mu0 * (float)CLEN
                                                  : mu0 * (1.f - lamL0) / (1.f - lam0);
    const float Sb1 = (fabsf(1.f - lam1) < 1e-9f) ? mu1 * (float)CLEN
                                                  : mu1 * (1.f - lamL1) / (1.f - lam1);

    float aa0 = 0.f, bb0 = 0.f, aa1 = 0.f, bb1 = 0.f;
    const float2* Sp = Sa + (size_t)b * (NCH * CP) + cp;
    for (int j = 0; j < chunk; ++j) {
        const float2 s = Sp[(size_t)j * CP];
        aa0 = lamL0 * aa0 + s.x;  bb0 = lamL0 * bb0 + Sb0;
        aa1 = lamL1 * aa1 + s.y;  bb1 = lamL1 * bb1 + Sb1;
    }

    const u32* V32 = (const u32*)Vb;
    const u32* R32 = (const u32*)Rb;
    u32*       Y32 = (u32*)Y;
    size_t idx = ((size_t)(b * Tn + chunk * CLEN)) * CP + cp;
    #pragma unroll 4
    for (int i = 0; i < CLEN; ++i, idx += CP) {
        const u32 vv = V32[idx];
        const u32 rr = R32[idx];
        const float v0 = bf2f((u16)vv), v1 = bf2f((u16)(vv >> 16));
        const float r0 = bf2f((u16)rr), r1 = bf2f((u16)(rr >> 16));
        const float wkv0 = (e10 * aa0 + e20 * v0) *
                           __builtin_amdgcn_rcpf(e10 * bb0 + e20 + 1e-6f);
        const float wkv1 = (e11 * aa1 + e21 * v1) *
                           __builtin_amdgcn_rcpf(e11 * bb1 + e21 + 1e-6f);
        Y32[idx] = (u32)f2bf(r0 * wkv0) | ((u32)f2bf(r1 * wkv1) << 16);
        aa0 = lam0 * aa0 + mu0 * v0;  bb0 = lam0 * bb0 + mu0;
        aa1 = lam1 * aa1 + mu1 * v1;  bb1 = lam1 * bb1 + mu1;
    }
}

extern "C" void kernel_launch(void* const* d_in, const int* in_sizes, int n_in,
                              void* d_out, int out_size, void* d_ws, size_t ws_size,
                              hipStream_t stream)
{
    // inputs: x, time_decay, time_first, key_w(dead), value_w, recep_w, out_w
    const float* x       = (const float*)d_in[0];
    const float* td      = (const float*)d_in[1];
    const float* tf      = (const float*)d_in[2];
    const float* value_w = (const float*)d_in[4];
    const float* recep_w = (const float*)d_in[5];
    const float* out_w   = (const float*)d_in[6];
    float* out = (float*)d_out;

    char* ws = (char*)d_ws;
    const size_t MB = 1024 * 1024;
    u16*    Xb  = (u16*)(ws);               // 32 MB; reused as Yb after gemm_vr+wkv
    u16*    Vb  = (u16*)(ws + 32 * MB);     // 32 MB
    u16*    Rb  = (u16*)(ws + 64 * MB);     // 32 MB
    u16*    Wvr = (u16*)(ws + 96 * MB);     //  4 MB  (concat [Wv; Wr], 2048 x 1024)
    u16*    Wo  = (u16*)(ws + 100 * MB);    //  2 MB
    float2* Sa  = (float2*)(ws + 102 * MB); //  2 MB [8][64][512] float2
    u16*    Yb  = Xb;                       // alias: Xb dead after gemm_vr

    cast_all<<<19456, 256, 0, stream>>>(x, value_w, recep_w, out_w, Xb, Wvr, Wo);

    gemm_vr<<<512, 512, 0, stream>>>(Xb, Wvr, Vb, Rb);

    const int nScan = Bn * NCH * CP;      // 262144 threads
    wkv_pass1<<<nScan / 256, 256, 0, stream>>>(Vb, td, Sa);
    wkv_pass2<<<nScan / 256, 256, 0, stream>>>(Vb, Rb, td, tf, Sa, Yb);

    gemm_out<<<256, 512, 0, stream>>>(Yb, Wo, out);
}